// Round 1
// 734.809 us; speedup vs baseline: 1.0062x; 1.0062x over previous
//
#include <hip/hip_runtime.h>

// MoE top-2 layer, MI355X — round 3.
// r3 changes vs r2 (739 us baseline):
//   * gemm_proj split-K 2 -> 4: grid 1072 -> 2144 active blocks (4.2 -> 8.4
//     blocks/CU). proj was latency/occupancy-bound (MfmaUtil 17%, VALUBusy 7%,
//     Occupancy 25%, HBM only 28% of peak) — resources allow 7 blocks/CU but
//     grid only supplied 4. Atomic write traffic doubles (BW headroom exists).
//   * fast gelu via v_exp_f32 (x / (1+exp(-2u))) — replaces libm tanhf
//     (~25 VALU ops -> ~5) in gemm_fc's 64-outputs-per-thread epilogue.
//   * zero launches merged; y zero via hipMemsetAsync.
//
// All GEMM operands pre-packed fp16 in [kb][row][32] layout (kb = k/32) so
// every 128x32 tile is one contiguous 8KB block -> global_load_lds width=16
// for BOTH operands.
//
// N=4096 tokens, C=1024, E=8, H=4096, top-2. NPC=9216 slot capacity
// (worst-case per-expert 128-alignment). ws required ~162 MB.

#define NTOK  4096
#define CDIM  1024
#define HDIM  4096
#define NEXP  8
#define NPC   9216
#define MAXMT 72
#define KB_C  32     // CDIM/32
#define KB_H  128    // HDIM/32
#define KSPLIT 4     // proj split-K slices

typedef _Float16 half8 __attribute__((ext_vector_type(8)));
typedef float    f32x4 __attribute__((ext_vector_type(4)));

// async global->LDS, 16B per lane. LDS dest = wave-uniform base + lane*16.
#define ASYNC_CP16(gp, lp)                                                         \
  __builtin_amdgcn_global_load_lds(                                                \
      (const __attribute__((address_space(1))) unsigned int*)(gp),                 \
      (__attribute__((address_space(3))) unsigned int*)(lp), 16, 0, 0)

__device__ __forceinline__ float gelu_new(float x) {
    // 0.5x(1+tanh(u)) == x * sigmoid(2u); robust at extremes:
    //   x << 0: exp(-2u) -> +inf, x/inf -> -0  (correct)
    //   x >> 0: exp(-2u) -> 0, result -> x     (correct)
    const float c = 0.7978845608028654f;  // sqrt(2/pi)
    float u = c * (x + 0.044715f * x * x * x);
    return x / (1.0f + __expf(-2.0f * u));
}

// ---------------- utility ----------------

__global__ void zero_init(unsigned int* __restrict__ pairs,   // pair_tok+pair_gate
                          unsigned int* __restrict__ counts) {
    int i = blockIdx.x * 256 + threadIdx.x;
    if (i < 2 * NPC) pairs[i] = 0u;
    if (i < NEXP) counts[i] = 0u;
}

// ---------------- routing ----------------

__global__ __launch_bounds__(256) void router_kernel(
    const float* __restrict__ x, const float* __restrict__ rw,
    int* __restrict__ tok_e, float* __restrict__ tok_w, int* __restrict__ counts)
{
    int wave = threadIdx.x >> 6, lane = threadIdx.x & 63;
    int n = blockIdx.x * 4 + wave;
    const float* xr = x + (size_t)n * CDIM;
    float acc[NEXP];
    #pragma unroll
    for (int e = 0; e < NEXP; ++e) acc[e] = 0.f;
    for (int c = lane; c < CDIM; c += 64) {
        float xv = xr[c];
        #pragma unroll
        for (int e = 0; e < NEXP; ++e) acc[e] = fmaf(xv, rw[e * CDIM + c], acc[e]);
    }
    #pragma unroll
    for (int e = 0; e < NEXP; ++e) {
        float v = acc[e];
        #pragma unroll
        for (int off = 32; off > 0; off >>= 1) v += __shfl_down(v, off);
        acc[e] = v;
    }
    if (lane == 0) {
        float l0 = -3.0e38f, l1 = -3.0e38f; int b0 = 0, b1 = 0;
        #pragma unroll
        for (int e = 0; e < NEXP; ++e) {
            float v = acc[e];
            if (v > l0)      { l1 = l0; b1 = b0; l0 = v; b0 = e; }
            else if (v > l1) { l1 = v; b1 = e; }
        }
        float t  = expf(l1 - l0);            // l1 <= l0, stable
        float w0 = 1.f / (1.f + t);
        float w1 = t  / (1.f + t);
        tok_e[n * 2]     = b0;  tok_e[n * 2 + 1] = b1;
        tok_w[n * 2]     = w0;  tok_w[n * 2 + 1] = w1;
        atomicAdd(&counts[b0], 1);
        atomicAdd(&counts[b1], 1);
    }
}

__global__ void plan_kernel(const int* __restrict__ counts, int* __restrict__ cursors,
                            int* __restrict__ mtiles, int* __restrict__ tile_expert)
{
    if (threadIdx.x == 0 && blockIdx.x == 0) {
        int b = 0;
        for (int e = 0; e < NEXP; ++e) {
            cursors[e] = b;
            int tiles = (counts[e] + 127) >> 7;
            for (int t = 0; t < tiles; ++t) tile_expert[(b >> 7) + t] = e;
            b += tiles << 7;
        }
        *mtiles = b >> 7;
        for (int t = b >> 7; t < MAXMT; ++t) tile_expert[t] = 0;
    }
}

__global__ void assign_kernel(const int* __restrict__ tok_e, const float* __restrict__ tok_w,
                              int* __restrict__ cursors,
                              int* __restrict__ pair_tok, float* __restrict__ pair_gate)
{
    int n = blockIdx.x * 256 + threadIdx.x;  // exactly NTOK threads
    #pragma unroll
    for (int k = 0; k < 2; ++k) {
        int e = tok_e[n * 2 + k];
        int slot = atomicAdd(&cursors[e], 1);
        pair_tok[slot]  = n;
        pair_gate[slot] = tok_w[n * 2 + k];
    }
}

// ---------------- A gather+convert into packed layout ----------------
// xg[kb][slot][kk] = fp16(x[pair_tok[slot]][kb*32+kk]); pad slots -> token 0.

__global__ __launch_bounds__(256) void gather_x_kernel(
    const float* __restrict__ x, const int* __restrict__ pair_tok,
    _Float16* __restrict__ xg)
{
    int o = blockIdx.x * 256 + threadIdx.x;          // KB_C * NPC * 4 threads
    int kb   = o / (NPC * 4);
    int rem  = o - kb * (NPC * 4);
    int slot = rem >> 2;
    int c    = (rem & 3) * 8;
    int tok  = pair_tok[slot];
    const float* src = x + (size_t)tok * CDIM + kb * 32 + c;
    float4 a = *(const float4*)src;
    float4 b = *(const float4*)(src + 4);
    half8 h;
    h[0] = (_Float16)a.x; h[1] = (_Float16)a.y; h[2] = (_Float16)a.z; h[3] = (_Float16)a.w;
    h[4] = (_Float16)b.x; h[5] = (_Float16)b.y; h[6] = (_Float16)b.z; h[7] = (_Float16)b.w;
    *(half8*)(xg + ((size_t)kb * NPC + slot) * 32 + c) = h;
}

// ---------------- weight transpose+convert ----------------
// w [E][K][N] fp32  ->  wt [E][K/32][N][32] fp16  (wt[e][kb][n][kk] = w[e][kb*32+kk][n])
// Block handles 32k x 64n tile via LDS. Reads and writes fully coalesced.

__global__ __launch_bounds__(256) void transpose_cvt_kernel(
    const float* __restrict__ w, _Float16* __restrict__ wt, int K, int N)
{
    __shared__ float tile[32][68];                   // 68: 16B-aligned rows, pad
    const int e = blockIdx.z, k0 = blockIdx.y * 32, n0 = blockIdx.x * 64;
    const float* src = w + ((size_t)e * K + k0) * N + n0;
    const int t = threadIdx.x;
    #pragma unroll
    for (int f = t; f < 512; f += 256) {             // 512 float4 = 32x64 floats
        int k = f >> 4, nc = (f & 15) * 4;
        *(float4*)&tile[k][nc] = *(const float4*)(src + (size_t)k * N + nc);
    }
    __syncthreads();
    int n = t >> 2, c2 = (t & 3) * 8;
    half8 h;
    #pragma unroll
    for (int q = 0; q < 8; ++q) h[q] = (_Float16)tile[c2 + q][n];
    int KB = K >> 5;
    _Float16* dst = wt + (((size_t)e * KB + (k0 >> 5)) * N + (n0 + n)) * 32 + c2;
    *(half8*)dst = h;
}

// ---------------- GEMM 1: hb = gelu(xg @ wt_fc + b_fc)  (packed in/out) ----------------
// 128x128 tile, BK=32, 4 waves x (4x4 mfma_f32_16x16x32_f16).

__global__ __launch_bounds__(256) void gemm_fc_kernel(
    const _Float16* __restrict__ xg,     // packed [KB_C][NPC][32]
    const _Float16* __restrict__ wt,     // packed [E][KB_C][HDIM][32]
    const float*    __restrict__ b_fc,   // [E][HDIM]
    const int*      __restrict__ tile_expert,
    const int*      __restrict__ mtiles,
    _Float16*       __restrict__ hb)     // packed [KB_H][NPC][32]
{
    const int mt = blockIdx.y;
    if (mt >= *mtiles) return;
    const int nt = blockIdx.x;
    const int e  = tile_expert[mt];
    const int m0 = mt << 7, n0 = nt << 7;

    __shared__ _Float16 As[128 * 32];
    __shared__ _Float16 Bs[128 * 32];

    const int tid = threadIdx.x;
    const int lane = tid & 63, wv = tid >> 6;
    const int wm = (wv >> 1) * 64, wn = (wv & 1) * 64;
    const int l16 = lane & 15, lq = lane >> 4;

    const char* gA0 = (const char*)xg + (size_t)m0 * 64;
    const char* gB0 = (const char*)wt + ((size_t)e * KB_C * HDIM + n0) * 64;
    const int soff = wv * 2048 + lane * 16;
    char* lA = (char*)As + wv * 2048;
    char* lB = (char*)Bs + wv * 2048;

    f32x4 acc[4][4];
    #pragma unroll
    for (int i = 0; i < 4; ++i)
        #pragma unroll
        for (int j = 0; j < 4; ++j) { acc[i][j][0]=0.f; acc[i][j][1]=0.f; acc[i][j][2]=0.f; acc[i][j][3]=0.f; }

    for (int kb = 0; kb < KB_C; ++kb) {
        const char* ga = gA0 + (size_t)kb * (NPC * 64) + soff;
        const char* gb = gB0 + (size_t)kb * (HDIM * 64) + soff;
        ASYNC_CP16(ga,        lA);
        ASYNC_CP16(ga + 1024, lA + 1024);
        ASYNC_CP16(gb,        lB);
        ASYNC_CP16(gb + 1024, lB + 1024);
        __syncthreads();
        half8 af[4], bfv[4];
        #pragma unroll
        for (int i = 0; i < 4; ++i) af[i]  = *(const half8*)&As[(wm + i * 16 + l16) * 32 + lq * 8];
        #pragma unroll
        for (int j = 0; j < 4; ++j) bfv[j] = *(const half8*)&Bs[(wn + j * 16 + l16) * 32 + lq * 8];
        #pragma unroll
        for (int i = 0; i < 4; ++i)
            #pragma unroll
            for (int j = 0; j < 4; ++j)
                acc[i][j] = __builtin_amdgcn_mfma_f32_16x16x32_f16(af[i], bfv[j], acc[i][j], 0, 0, 0);
        __syncthreads();
    }

    float bias[4];
    #pragma unroll
    for (int j = 0; j < 4; ++j) bias[j] = b_fc[e * HDIM + n0 + wn + j * 16 + l16];
    #pragma unroll
    for (int i = 0; i < 4; ++i) {
        #pragma unroll
        for (int r = 0; r < 4; ++r) {
            int slot = m0 + wm + i * 16 + lq * 4 + r;   // D row = quad*4 + reg
            #pragma unroll
            for (int j = 0; j < 4; ++j) {
                int n = n0 + wn + j * 16 + l16;          // D col = lane&15
                float v = gelu_new(acc[i][j][r] + bias[j]);
                hb[((size_t)(n >> 5) * NPC + slot) * 32 + (n & 31)] = (_Float16)v;
            }
        }
    }
}

// ---------------- GEMM 2: y[tok] += gate * (hb @ wt_proj + b_proj), split-K=4 ----------------

__global__ __launch_bounds__(256) void gemm_proj_kernel(
    const _Float16* __restrict__ hb,     // packed [KB_H][NPC][32]
    const _Float16* __restrict__ wt,     // packed [E][KB_H][CDIM][32]
    const float*    __restrict__ b_proj, // [E][CDIM]
    const int*      __restrict__ pair_tok,
    const float*    __restrict__ pair_gate,
    const int*      __restrict__ tile_expert,
    const int*      __restrict__ mtiles,
    float*          __restrict__ y)      // [NTOK][CDIM]
{
    const int mt = blockIdx.y;
    if (mt >= *mtiles) return;
    const int nt = blockIdx.x;
    const int ks = blockIdx.z;           // split-K slice: kb in [ks*32, ks*32+32)
    const int e  = tile_expert[mt];
    const int m0 = mt << 7, n0 = nt << 7;

    __shared__ _Float16 As[128 * 32];
    __shared__ _Float16 Bs[128 * 32];

    const int tid = threadIdx.x;
    const int lane = tid & 63, wv = tid >> 6;
    const int wm = (wv >> 1) * 64, wn = (wv & 1) * 64;
    const int l16 = lane & 15, lq = lane >> 4;

    const char* gA0 = (const char*)hb + (size_t)m0 * 64;
    const char* gB0 = (const char*)wt + ((size_t)e * KB_H * CDIM + n0) * 64;
    const int soff = wv * 2048 + lane * 16;
    char* lA = (char*)As + wv * 2048;
    char* lB = (char*)Bs + wv * 2048;

    f32x4 acc[4][4];
    #pragma unroll
    for (int i = 0; i < 4; ++i)
        #pragma unroll
        for (int j = 0; j < 4; ++j) { acc[i][j][0]=0.f; acc[i][j][1]=0.f; acc[i][j][2]=0.f; acc[i][j][3]=0.f; }

    const int kb_beg = ks * (KB_H / KSPLIT);
    const int kb_end = kb_beg + (KB_H / KSPLIT);
    for (int kb = kb_beg; kb < kb_end; ++kb) {
        const char* ga = gA0 + (size_t)kb * (NPC * 64) + soff;
        const char* gb = gB0 + (size_t)kb * (CDIM * 64) + soff;
        ASYNC_CP16(ga,        lA);
        ASYNC_CP16(ga + 1024, lA + 1024);
        ASYNC_CP16(gb,        lB);
        ASYNC_CP16(gb + 1024, lB + 1024);
        __syncthreads();
        half8 af[4], bfv[4];
        #pragma unroll
        for (int i = 0; i < 4; ++i) af[i]  = *(const half8*)&As[(wm + i * 16 + l16) * 32 + lq * 8];
        #pragma unroll
        for (int j = 0; j < 4; ++j) bfv[j] = *(const half8*)&Bs[(wn + j * 16 + l16) * 32 + lq * 8];
        #pragma unroll
        for (int i = 0; i < 4; ++i)
            #pragma unroll
            for (int j = 0; j < 4; ++j)
                acc[i][j] = __builtin_amdgcn_mfma_f32_16x16x32_f16(af[i], bfv[j], acc[i][j], 0, 0, 0);
        __syncthreads();
    }

    float bias[4];
    #pragma unroll
    for (int j = 0; j < 4; ++j)
        bias[j] = (ks == 0) ? b_proj[e * CDIM + n0 + wn + j * 16 + l16] : 0.0f;
    #pragma unroll
    for (int i = 0; i < 4; ++i) {
        #pragma unroll
        for (int r = 0; r < 4; ++r) {
            int slot = m0 + wm + i * 16 + lq * 4 + r;
            float g  = pair_gate[slot];
            if (g != 0.0f) {
                int tok = pair_tok[slot];
                float* dst = y + (size_t)tok * CDIM + n0 + wn + l16;
                #pragma unroll
                for (int j = 0; j < 4; ++j)
                    atomicAdd(&dst[j * 16], (acc[i][j][r] + bias[j]) * g);
            }
        }
    }
}

// ---------------- launch ----------------

extern "C" void kernel_launch(void* const* d_in, const int* in_sizes, int n_in,
                              void* d_out, int out_size, void* d_ws, size_t ws_size,
                              hipStream_t stream) {
    const float* x   = (const float*)d_in[0];
    const float* rw  = (const float*)d_in[1];
    const float* wfc = (const float*)d_in[2];
    const float* bfc = (const float*)d_in[3];
    const float* wpj = (const float*)d_in[4];
    const float* bpj = (const float*)d_in[5];
    float* y = (float*)d_out;

    char* ws = (char*)d_ws;
    // workspace layout (bytes), total ~161.7 MB
    _Float16* xg  = (_Float16*)(ws);                    // 18,874,368  [KB_C][NPC][32]
    _Float16* hb  = (_Float16*)(ws + 18874368);         // 75,497,472  [KB_H][NPC][32]
    _Float16* wt  = (_Float16*)(ws + 94371840);         // 67,108,864  shared fc/proj
    char* meta = ws + 161480704;
    int*   pair_tok    = (int*)  (meta);                //  36,864
    float* pair_gate   = (float*)(meta + 36864);        //  36,864 (contiguous after pair_tok)
    int*   tok_e       = (int*)  (meta + 73728);        //  32,768
    float* tok_w       = (float*)(meta + 106496);       //  32,768
    int*   counts      = (int*)  (meta + 139264);       // 8
    int*   cursors     = counts + 8;                    // 8
    int*   mtiles      = cursors + 8;                   // 1 (+pad)
    int*   tile_expert = mtiles + 2;                    // 72

    hipMemsetAsync(y, 0, (size_t)NTOK * CDIM * sizeof(float), stream);
    zero_init<<<(2 * NPC) / 256, 256, 0, stream>>>((unsigned int*)pair_tok,
                                                   (unsigned int*)counts);

    router_kernel<<<1024, 256, 0, stream>>>(x, rw, tok_e, tok_w, counts);
    plan_kernel<<<1, 64, 0, stream>>>(counts, cursors, mtiles, tile_expert);
    assign_kernel<<<16, 256, 0, stream>>>(tok_e, tok_w, cursors, pair_tok, pair_gate);
    gather_x_kernel<<<KB_C * NPC * 4 / 256, 256, 0, stream>>>(x, pair_tok, xg);

    // fc: transpose w_fc -> wt, then GEMM into hb
    transpose_cvt_kernel<<<dim3(HDIM / 64, CDIM / 32, NEXP), 256, 0, stream>>>(wfc, wt, CDIM, HDIM);
    gemm_fc_kernel<<<dim3(HDIM / 128, MAXMT), 256, 0, stream>>>(
        xg, wt, bfc, tile_expert, mtiles, hb);

    // proj: transpose w_proj -> wt (reuse buffer), then GEMM into y
    transpose_cvt_kernel<<<dim3(CDIM / 64, HDIM / 32, NEXP), 256, 0, stream>>>(wpj, wt, HDIM, CDIM);
    gemm_proj_kernel<<<dim3(CDIM / 128, MAXMT, KSPLIT), 256, 0, stream>>>(
        hb, wt, bpj, pair_tok, pair_gate, tile_expert, mtiles, y);
}

// Round 2
// 717.369 us; speedup vs baseline: 1.0307x; 1.0243x over previous
//
#include <hip/hip_runtime.h>

// MoE top-2 layer, MI355X — round 4.
// r4 changes vs r3 (735 us):
//   * Revert proj split-K 4 -> 2 (r3 post-mortem: KSPLIT=4 regressed proj
//     172 -> 193 us; extra atomic RMW traffic, no occupancy payoff).
//   * XCD-aware chunked block swizzle (T1) in BOTH GEMMs. Root cause of
//     proj's 310 MB FETCH (vs 142 MB unique): nt is the fastest grid dim, so
//     the 8 blocks sharing one A-panel round-robin onto 8 different XCDs ->
//     A (hb / xg) is re-fetched by every XCD L2. Chunked swizzle gives each
//     XCD a contiguous run of mt-tiles (all nt), restoring A-panel reuse in
//     its private L2. Grids are multiples of 8 -> simple bijective formula.
//   * Keep fast gelu (v_exp_f32 sigmoid form).
//
// All GEMM operands pre-packed fp16 in [kb][row][32] layout (kb = k/32) so
// every 128x32 tile is one contiguous 8KB block -> global_load_lds width=16
// for BOTH operands.
//
// N=4096 tokens, C=1024, E=8, H=4096, top-2. NPC=9216 slot capacity
// (worst-case per-expert 128-alignment). ws required ~162 MB.

#define NTOK  4096
#define CDIM  1024
#define HDIM  4096
#define NEXP  8
#define NPC   9216
#define MAXMT 72
#define KB_C  32     // CDIM/32
#define KB_H  128    // HDIM/32
#define KSPLIT 2     // proj split-K slices

// swizzle chunk sizes (blocks per XCD)
#define FC_TOTAL (32 * MAXMT)          // 2304
#define FC_CHUNK (FC_TOTAL / 8)        // 288
#define PJ_TOTAL (8 * MAXMT * KSPLIT)  // 1152
#define PJ_CHUNK (PJ_TOTAL / 8)        // 144

typedef _Float16 half8 __attribute__((ext_vector_type(8)));
typedef float    f32x4 __attribute__((ext_vector_type(4)));

// async global->LDS, 16B per lane. LDS dest = wave-uniform base + lane*16.
#define ASYNC_CP16(gp, lp)                                                         \
  __builtin_amdgcn_global_load_lds(                                                \
      (const __attribute__((address_space(1))) unsigned int*)(gp),                 \
      (__attribute__((address_space(3))) unsigned int*)(lp), 16, 0, 0)

__device__ __forceinline__ float gelu_new(float x) {
    // 0.5x(1+tanh(u)) == x * sigmoid(2u); robust at extremes.
    const float c = 0.7978845608028654f;  // sqrt(2/pi)
    float u = c * (x + 0.044715f * x * x * x);
    return x / (1.0f + __expf(-2.0f * u));
}

// ---------------- utility ----------------

__global__ void zero_init(unsigned int* __restrict__ pairs,   // pair_tok+pair_gate
                          unsigned int* __restrict__ counts) {
    int i = blockIdx.x * 256 + threadIdx.x;
    if (i < 2 * NPC) pairs[i] = 0u;
    if (i < NEXP) counts[i] = 0u;
}

// ---------------- routing ----------------

__global__ __launch_bounds__(256) void router_kernel(
    const float* __restrict__ x, const float* __restrict__ rw,
    int* __restrict__ tok_e, float* __restrict__ tok_w, int* __restrict__ counts)
{
    int wave = threadIdx.x >> 6, lane = threadIdx.x & 63;
    int n = blockIdx.x * 4 + wave;
    const float* xr = x + (size_t)n * CDIM;
    float acc[NEXP];
    #pragma unroll
    for (int e = 0; e < NEXP; ++e) acc[e] = 0.f;
    for (int c = lane; c < CDIM; c += 64) {
        float xv = xr[c];
        #pragma unroll
        for (int e = 0; e < NEXP; ++e) acc[e] = fmaf(xv, rw[e * CDIM + c], acc[e]);
    }
    #pragma unroll
    for (int e = 0; e < NEXP; ++e) {
        float v = acc[e];
        #pragma unroll
        for (int off = 32; off > 0; off >>= 1) v += __shfl_down(v, off);
        acc[e] = v;
    }
    if (lane == 0) {
        float l0 = -3.0e38f, l1 = -3.0e38f; int b0 = 0, b1 = 0;
        #pragma unroll
        for (int e = 0; e < NEXP; ++e) {
            float v = acc[e];
            if (v > l0)      { l1 = l0; b1 = b0; l0 = v; b0 = e; }
            else if (v > l1) { l1 = v; b1 = e; }
        }
        float t  = expf(l1 - l0);            // l1 <= l0, stable
        float w0 = 1.f / (1.f + t);
        float w1 = t  / (1.f + t);
        tok_e[n * 2]     = b0;  tok_e[n * 2 + 1] = b1;
        tok_w[n * 2]     = w0;  tok_w[n * 2 + 1] = w1;
        atomicAdd(&counts[b0], 1);
        atomicAdd(&counts[b1], 1);
    }
}

__global__ void plan_kernel(const int* __restrict__ counts, int* __restrict__ cursors,
                            int* __restrict__ mtiles, int* __restrict__ tile_expert)
{
    if (threadIdx.x == 0 && blockIdx.x == 0) {
        int b = 0;
        for (int e = 0; e < NEXP; ++e) {
            cursors[e] = b;
            int tiles = (counts[e] + 127) >> 7;
            for (int t = 0; t < tiles; ++t) tile_expert[(b >> 7) + t] = e;
            b += tiles << 7;
        }
        *mtiles = b >> 7;
        for (int t = b >> 7; t < MAXMT; ++t) tile_expert[t] = 0;
    }
}

__global__ void assign_kernel(const int* __restrict__ tok_e, const float* __restrict__ tok_w,
                              int* __restrict__ cursors,
                              int* __restrict__ pair_tok, float* __restrict__ pair_gate)
{
    int n = blockIdx.x * 256 + threadIdx.x;  // exactly NTOK threads
    #pragma unroll
    for (int k = 0; k < 2; ++k) {
        int e = tok_e[n * 2 + k];
        int slot = atomicAdd(&cursors[e], 1);
        pair_tok[slot]  = n;
        pair_gate[slot] = tok_w[n * 2 + k];
    }
}

// ---------------- A gather+convert into packed layout ----------------
// xg[kb][slot][kk] = fp16(x[pair_tok[slot]][kb*32+kk]); pad slots -> token 0.

__global__ __launch_bounds__(256) void gather_x_kernel(
    const float* __restrict__ x, const int* __restrict__ pair_tok,
    _Float16* __restrict__ xg)
{
    int o = blockIdx.x * 256 + threadIdx.x;          // KB_C * NPC * 4 threads
    int kb   = o / (NPC * 4);
    int rem  = o - kb * (NPC * 4);
    int slot = rem >> 2;
    int c    = (rem & 3) * 8;
    int tok  = pair_tok[slot];
    const float* src = x + (size_t)tok * CDIM + kb * 32 + c;
    float4 a = *(const float4*)src;
    float4 b = *(const float4*)(src + 4);
    half8 h;
    h[0] = (_Float16)a.x; h[1] = (_Float16)a.y; h[2] = (_Float16)a.z; h[3] = (_Float16)a.w;
    h[4] = (_Float16)b.x; h[5] = (_Float16)b.y; h[6] = (_Float16)b.z; h[7] = (_Float16)b.w;
    *(half8*)(xg + ((size_t)kb * NPC + slot) * 32 + c) = h;
}

// ---------------- weight transpose+convert ----------------
// w [E][K][N] fp32  ->  wt [E][K/32][N][32] fp16  (wt[e][kb][n][kk] = w[e][kb*32+kk][n])
// Block handles 32k x 64n tile via LDS. Reads and writes fully coalesced.

__global__ __launch_bounds__(256) void transpose_cvt_kernel(
    const float* __restrict__ w, _Float16* __restrict__ wt, int K, int N)
{
    __shared__ float tile[32][68];                   // 68: 16B-aligned rows, pad
    const int e = blockIdx.z, k0 = blockIdx.y * 32, n0 = blockIdx.x * 64;
    const float* src = w + ((size_t)e * K + k0) * N + n0;
    const int t = threadIdx.x;
    #pragma unroll
    for (int f = t; f < 512; f += 256) {             // 512 float4 = 32x64 floats
        int k = f >> 4, nc = (f & 15) * 4;
        *(float4*)&tile[k][nc] = *(const float4*)(src + (size_t)k * N + nc);
    }
    __syncthreads();
    int n = t >> 2, c2 = (t & 3) * 8;
    half8 h;
    #pragma unroll
    for (int q = 0; q < 8; ++q) h[q] = (_Float16)tile[c2 + q][n];
    int KB = K >> 5;
    _Float16* dst = wt + (((size_t)e * KB + (k0 >> 5)) * N + (n0 + n)) * 32 + c2;
    *(half8*)dst = h;
}

// ---------------- GEMM 1: hb = gelu(xg @ wt_fc + b_fc)  (packed in/out) ----------------
// 128x128 tile, BK=32, 4 waves x (4x4 mfma_f32_16x16x32_f16).
// XCD chunked swizzle: each XCD gets 9 consecutive mt (all 32 nt) so the
// A-panel (xg rows) is reused from its private L2 instead of re-fetched.

__global__ __launch_bounds__(256) void gemm_fc_kernel(
    const _Float16* __restrict__ xg,     // packed [KB_C][NPC][32]
    const _Float16* __restrict__ wt,     // packed [E][KB_C][HDIM][32]
    const float*    __restrict__ b_fc,   // [E][HDIM]
    const int*      __restrict__ tile_expert,
    const int*      __restrict__ mtiles,
    _Float16*       __restrict__ hb)     // packed [KB_H][NPC][32]
{
    // ---- XCD chunked swizzle (bijective: FC_TOTAL % 8 == 0) ----
    const unsigned flat = blockIdx.y * 32u + blockIdx.x;
    const unsigned logical = (flat & 7u) * FC_CHUNK + (flat >> 3);
    const int nt = logical & 31;          // 32 nt, fastest
    const int mt = logical >> 5;
    if (mt >= *mtiles) return;
    const int e  = tile_expert[mt];
    const int m0 = mt << 7, n0 = nt << 7;

    __shared__ _Float16 As[128 * 32];
    __shared__ _Float16 Bs[128 * 32];

    const int tid = threadIdx.x;
    const int lane = tid & 63, wv = tid >> 6;
    const int wm = (wv >> 1) * 64, wn = (wv & 1) * 64;
    const int l16 = lane & 15, lq = lane >> 4;

    const char* gA0 = (const char*)xg + (size_t)m0 * 64;
    const char* gB0 = (const char*)wt + ((size_t)e * KB_C * HDIM + n0) * 64;
    const int soff = wv * 2048 + lane * 16;
    char* lA = (char*)As + wv * 2048;
    char* lB = (char*)Bs + wv * 2048;

    f32x4 acc[4][4];
    #pragma unroll
    for (int i = 0; i < 4; ++i)
        #pragma unroll
        for (int j = 0; j < 4; ++j) { acc[i][j][0]=0.f; acc[i][j][1]=0.f; acc[i][j][2]=0.f; acc[i][j][3]=0.f; }

    for (int kb = 0; kb < KB_C; ++kb) {
        const char* ga = gA0 + (size_t)kb * (NPC * 64) + soff;
        const char* gb = gB0 + (size_t)kb * (HDIM * 64) + soff;
        ASYNC_CP16(ga,        lA);
        ASYNC_CP16(ga + 1024, lA + 1024);
        ASYNC_CP16(gb,        lB);
        ASYNC_CP16(gb + 1024, lB + 1024);
        __syncthreads();
        half8 af[4], bfv[4];
        #pragma unroll
        for (int i = 0; i < 4; ++i) af[i]  = *(const half8*)&As[(wm + i * 16 + l16) * 32 + lq * 8];
        #pragma unroll
        for (int j = 0; j < 4; ++j) bfv[j] = *(const half8*)&Bs[(wn + j * 16 + l16) * 32 + lq * 8];
        #pragma unroll
        for (int i = 0; i < 4; ++i)
            #pragma unroll
            for (int j = 0; j < 4; ++j)
                acc[i][j] = __builtin_amdgcn_mfma_f32_16x16x32_f16(af[i], bfv[j], acc[i][j], 0, 0, 0);
        __syncthreads();
    }

    float bias[4];
    #pragma unroll
    for (int j = 0; j < 4; ++j) bias[j] = b_fc[e * HDIM + n0 + wn + j * 16 + l16];
    #pragma unroll
    for (int i = 0; i < 4; ++i) {
        #pragma unroll
        for (int r = 0; r < 4; ++r) {
            int slot = m0 + wm + i * 16 + lq * 4 + r;   // D row = quad*4 + reg
            #pragma unroll
            for (int j = 0; j < 4; ++j) {
                int n = n0 + wn + j * 16 + l16;          // D col = lane&15
                float v = gelu_new(acc[i][j][r] + bias[j]);
                hb[((size_t)(n >> 5) * NPC + slot) * 32 + (n & 31)] = (_Float16)v;
            }
        }
    }
}

// ---------------- GEMM 2: y[tok] += gate * (hb @ wt_proj + b_proj), split-K=2 ----------------
// XCD chunked swizzle: each XCD gets 18 consecutive mt (all 8 nt, one ks).

__global__ __launch_bounds__(256) void gemm_proj_kernel(
    const _Float16* __restrict__ hb,     // packed [KB_H][NPC][32]
    const _Float16* __restrict__ wt,     // packed [E][KB_H][CDIM][32]
    const float*    __restrict__ b_proj, // [E][CDIM]
    const int*      __restrict__ pair_tok,
    const float*    __restrict__ pair_gate,
    const int*      __restrict__ tile_expert,
    const int*      __restrict__ mtiles,
    float*          __restrict__ y)      // [NTOK][CDIM]
{
    // ---- XCD chunked swizzle (bijective: PJ_TOTAL % 8 == 0) ----
    const unsigned flat = (blockIdx.z * MAXMT + blockIdx.y) * 8u + blockIdx.x;
    const unsigned logical = (flat & 7u) * PJ_CHUNK + (flat >> 3);
    const int nt = logical & 7;                       // 8 nt, fastest
    const unsigned t2 = logical >> 3;
    const int mt = t2 % MAXMT;
    const int ks = t2 / MAXMT;                        // split-K slice
    if (mt >= *mtiles) return;
    const int e  = tile_expert[mt];
    const int m0 = mt << 7, n0 = nt << 7;

    __shared__ _Float16 As[128 * 32];
    __shared__ _Float16 Bs[128 * 32];

    const int tid = threadIdx.x;
    const int lane = tid & 63, wv = tid >> 6;
    const int wm = (wv >> 1) * 64, wn = (wv & 1) * 64;
    const int l16 = lane & 15, lq = lane >> 4;

    const char* gA0 = (const char*)hb + (size_t)m0 * 64;
    const char* gB0 = (const char*)wt + ((size_t)e * KB_H * CDIM + n0) * 64;
    const int soff = wv * 2048 + lane * 16;
    char* lA = (char*)As + wv * 2048;
    char* lB = (char*)Bs + wv * 2048;

    f32x4 acc[4][4];
    #pragma unroll
    for (int i = 0; i < 4; ++i)
        #pragma unroll
        for (int j = 0; j < 4; ++j) { acc[i][j][0]=0.f; acc[i][j][1]=0.f; acc[i][j][2]=0.f; acc[i][j][3]=0.f; }

    const int kb_beg = ks * (KB_H / KSPLIT);
    const int kb_end = kb_beg + (KB_H / KSPLIT);
    for (int kb = kb_beg; kb < kb_end; ++kb) {
        const char* ga = gA0 + (size_t)kb * (NPC * 64) + soff;
        const char* gb = gB0 + (size_t)kb * (CDIM * 64) + soff;
        ASYNC_CP16(ga,        lA);
        ASYNC_CP16(ga + 1024, lA + 1024);
        ASYNC_CP16(gb,        lB);
        ASYNC_CP16(gb + 1024, lB + 1024);
        __syncthreads();
        half8 af[4], bfv[4];
        #pragma unroll
        for (int i = 0; i < 4; ++i) af[i]  = *(const half8*)&As[(wm + i * 16 + l16) * 32 + lq * 8];
        #pragma unroll
        for (int j = 0; j < 4; ++j) bfv[j] = *(const half8*)&Bs[(wn + j * 16 + l16) * 32 + lq * 8];
        #pragma unroll
        for (int i = 0; i < 4; ++i)
            #pragma unroll
            for (int j = 0; j < 4; ++j)
                acc[i][j] = __builtin_amdgcn_mfma_f32_16x16x32_f16(af[i], bfv[j], acc[i][j], 0, 0, 0);
        __syncthreads();
    }

    float bias[4];
    #pragma unroll
    for (int j = 0; j < 4; ++j)
        bias[j] = (ks == 0) ? b_proj[e * CDIM + n0 + wn + j * 16 + l16] : 0.0f;
    #pragma unroll
    for (int i = 0; i < 4; ++i) {
        #pragma unroll
        for (int r = 0; r < 4; ++r) {
            int slot = m0 + wm + i * 16 + lq * 4 + r;
            float g  = pair_gate[slot];
            if (g != 0.0f) {
                int tok = pair_tok[slot];
                float* dst = y + (size_t)tok * CDIM + n0 + wn + l16;
                #pragma unroll
                for (int j = 0; j < 4; ++j)
                    atomicAdd(&dst[j * 16], (acc[i][j][r] + bias[j]) * g);
            }
        }
    }
}

// ---------------- launch ----------------

extern "C" void kernel_launch(void* const* d_in, const int* in_sizes, int n_in,
                              void* d_out, int out_size, void* d_ws, size_t ws_size,
                              hipStream_t stream) {
    const float* x   = (const float*)d_in[0];
    const float* rw  = (const float*)d_in[1];
    const float* wfc = (const float*)d_in[2];
    const float* bfc = (const float*)d_in[3];
    const float* wpj = (const float*)d_in[4];
    const float* bpj = (const float*)d_in[5];
    float* y = (float*)d_out;

    char* ws = (char*)d_ws;
    // workspace layout (bytes), total ~161.7 MB
    _Float16* xg  = (_Float16*)(ws);                    // 18,874,368  [KB_C][NPC][32]
    _Float16* hb  = (_Float16*)(ws + 18874368);         // 75,497,472  [KB_H][NPC][32]
    _Float16* wt  = (_Float16*)(ws + 94371840);         // 67,108,864  shared fc/proj
    char* meta = ws + 161480704;
    int*   pair_tok    = (int*)  (meta);                //  36,864
    float* pair_gate   = (float*)(meta + 36864);        //  36,864 (contiguous after pair_tok)
    int*   tok_e       = (int*)  (meta + 73728);        //  32,768
    float* tok_w       = (float*)(meta + 106496);       //  32,768
    int*   counts      = (int*)  (meta + 139264);       // 8
    int*   cursors     = counts + 8;                    // 8
    int*   mtiles      = cursors + 8;                   // 1 (+pad)
    int*   tile_expert = mtiles + 2;                    // 72

    hipMemsetAsync(y, 0, (size_t)NTOK * CDIM * sizeof(float), stream);
    zero_init<<<(2 * NPC) / 256, 256, 0, stream>>>((unsigned int*)pair_tok,
                                                   (unsigned int*)counts);

    router_kernel<<<1024, 256, 0, stream>>>(x, rw, tok_e, tok_w, counts);
    plan_kernel<<<1, 64, 0, stream>>>(counts, cursors, mtiles, tile_expert);
    assign_kernel<<<16, 256, 0, stream>>>(tok_e, tok_w, cursors, pair_tok, pair_gate);
    gather_x_kernel<<<KB_C * NPC * 4 / 256, 256, 0, stream>>>(x, pair_tok, xg);

    // fc: transpose w_fc -> wt, then GEMM into hb
    transpose_cvt_kernel<<<dim3(HDIM / 64, CDIM / 32, NEXP), 256, 0, stream>>>(wfc, wt, CDIM, HDIM);
    gemm_fc_kernel<<<dim3(HDIM / 128, MAXMT), 256, 0, stream>>>(
        xg, wt, bfc, tile_expert, mtiles, hb);

    // proj: transpose w_proj -> wt (reuse buffer), then GEMM into y
    transpose_cvt_kernel<<<dim3(CDIM / 64, HDIM / 32, NEXP), 256, 0, stream>>>(wpj, wt, HDIM, CDIM);
    gemm_proj_kernel<<<dim3(CDIM / 128, MAXMT, KSPLIT), 256, 0, stream>>>(
        hb, wt, bpj, pair_tok, pair_gate, tile_expert, mtiles, y);
}